// Round 1
// baseline (4335.718 us; speedup 1.0000x reference)
//
#include <hip/hip_runtime.h>
#include <math.h>

#define B_  32
#define N_  256
#define D_  1024
#define H_  16
#define E_  512
#define ED_ 256
#define HD_ 64
#define NEG_ (-3.4028234663852886e38f)

// ---------------- LayerNorm: one block per row (B*N rows, D=1024) -------------
__global__ __launch_bounds__(256) void ln_kernel(const float* __restrict__ x,
                                                 const float* __restrict__ g,
                                                 const float* __restrict__ b,
                                                 float* __restrict__ out) {
    int row = blockIdx.x;
    const float* xr = x + (size_t)row * D_;
    float* yr = out + (size_t)row * D_;
    __shared__ float red[256];
    int t = threadIdx.x;
    float vals[4];
    float s = 0.f;
#pragma unroll
    for (int i = 0; i < 4; ++i) { vals[i] = xr[t + i * 256]; s += vals[i]; }
    red[t] = s; __syncthreads();
    for (int off = 128; off > 0; off >>= 1) { if (t < off) red[t] += red[t + off]; __syncthreads(); }
    float mean = red[0] * (1.f / D_);
    __syncthreads();
    float vs = 0.f;
#pragma unroll
    for (int i = 0; i < 4; ++i) { float d = vals[i] - mean; vs += d * d; }
    red[t] = vs; __syncthreads();
    for (int off = 128; off > 0; off >>= 1) { if (t < off) red[t] += red[t + off]; __syncthreads(); }
    float rstd = 1.f / sqrtf(red[0] * (1.f / D_) + 1e-5f);
#pragma unroll
    for (int i = 0; i < 4; ++i) {
        int c = t + i * 256;
        yr[c] = (vals[i] - mean) * rstd * g[c] + b[c];
    }
}

// ---------------- edge-bias projection: eb[b,e,h] = remb[b,e,:]·We[:,h]+be ----
__global__ void eb_kernel(const float* __restrict__ re, const float* __restrict__ We,
                          const float* __restrict__ be, float* __restrict__ eb) {
    int idx = blockIdx.x * blockDim.x + threadIdx.x;   // (b*E+e)*H + h
    if (idx >= B_ * E_ * H_) return;
    int h = idx & (H_ - 1);
    int bex = idx / H_;
    const float* r = re + (size_t)bex * ED_;
    float s = be[h];
    for (int i = 0; i < ED_; ++i) s += r[i] * We[i * H_ + h];
    eb[idx] = s;
}

// ---------------- edge scatter: last-writer-wins priority table --------------
// forward (src,dst) -> prio e ; reverse (dst,src) -> prio E+e (reverse scatter
// runs after forward in the reference, so any reverse beats any forward).
__global__ void scatter_kernel(const int* __restrict__ edges, const float* __restrict__ emask,
                               int* __restrict__ prio) {
    int idx = blockIdx.x * blockDim.x + threadIdx.x;   // b*E + e
    if (idx >= B_ * E_) return;
    if (emask[idx] == 0.f) return;
    int b = idx / E_, e = idx % E_;
    int s = edges[2 * idx], d = edges[2 * idx + 1];
    s = min(max(s, 0), N_ - 1);
    d = min(max(d, 0), N_ - 1);
    int* base = prio + (size_t)b * N_ * N_;
    atomicMax(&base[s * N_ + d], e);
    atomicMax(&base[d * N_ + s], e + E_);
}

// ---------------- fp32 tiled GEMM: C[M,N] = A[M,K]*B[K,N] (+epilogue) --------
// MODE 0: +bias   1: +bias+residual   2: silu(x+bias)   3: C += A*B
#define BM 64
#define BN 64
#define BK 16
template<int MODE>
__global__ __launch_bounds__(256) void gemm_kernel(
    const float* __restrict__ A, const float* __restrict__ Bm,
    const float* __restrict__ bias, const float* __restrict__ res,
    float* __restrict__ C, int M, int N, int K, int lda, int ldb, int ldc)
{
    __shared__ float As[BK][BM + 4];
    __shared__ float Bs[BK][BN + 4];
    int t = threadIdx.x;
    int tr = t >> 4, tc = t & 15;              // 16x16 threads, 4x4 each
    int row0 = blockIdx.y * BM, col0 = blockIdx.x * BN;
    int la_r = t >> 2;                         // 0..63
    int la_k = (t & 3) * 4;
    int lb_k = t >> 4;                         // 0..15
    int lb_c = (t & 15) * 4;
    float acc[4][4] = {};
    for (int k0 = 0; k0 < K; k0 += BK) {
        float4 av = *(const float4*)(A + (size_t)(row0 + la_r) * lda + k0 + la_k);
        As[la_k + 0][la_r] = av.x; As[la_k + 1][la_r] = av.y;
        As[la_k + 2][la_r] = av.z; As[la_k + 3][la_r] = av.w;
        float4 bv = *(const float4*)(Bm + (size_t)(k0 + lb_k) * ldb + col0 + lb_c);
        Bs[lb_k][lb_c + 0] = bv.x; Bs[lb_k][lb_c + 1] = bv.y;
        Bs[lb_k][lb_c + 2] = bv.z; Bs[lb_k][lb_c + 3] = bv.w;
        __syncthreads();
#pragma unroll
        for (int kk = 0; kk < BK; ++kk) {
            float4 a4 = *(const float4*)&As[kk][tr * 4];
            float4 b4 = *(const float4*)&Bs[kk][tc * 4];
            float aa[4] = {a4.x, a4.y, a4.z, a4.w};
            float bb[4] = {b4.x, b4.y, b4.z, b4.w};
#pragma unroll
            for (int i = 0; i < 4; ++i)
#pragma unroll
                for (int j = 0; j < 4; ++j)
                    acc[i][j] += aa[i] * bb[j];
        }
        __syncthreads();
    }
#pragma unroll
    for (int i = 0; i < 4; ++i) {
        int r = row0 + tr * 4 + i;
#pragma unroll
        for (int j = 0; j < 4; ++j) {
            int c = col0 + tc * 4 + j;
            float val = acc[i][j];
            if (MODE == 0) {
                val += bias[c];
            } else if (MODE == 1) {
                val += bias[c] + res[(size_t)r * ldc + c];
            } else if (MODE == 2) {
                val += bias[c];
                val = val / (1.f + __expf(-val));
            } else { // MODE == 3
                val += C[(size_t)r * ldc + c];
            }
            C[(size_t)r * ldc + c] = val;
        }
    }
}

// ---------------- attention: one block (256 thr) per (b,h,q) row -------------
__global__ __launch_bounds__(256) void attn_kernel(
    const float* __restrict__ q, const float* __restrict__ k,
    const float* __restrict__ v, const int* __restrict__ prio,
    const float* __restrict__ eb, const float* __restrict__ nm,
    float* __restrict__ out) {
    int bid = blockIdx.x;
    int qi = bid & (N_ - 1);
    int bh = bid >> 8;
    int h  = bh & (H_ - 1);
    int b  = bh >> 4;
    int t  = threadIdx.x;      // 256: thread t owns key t

    __shared__ float qrow[HD_];
    __shared__ float ps[N_];
    __shared__ float red[256];

    if (t < HD_) qrow[t] = q[(size_t)(b * N_ + qi) * D_ + h * HD_ + t];
    __syncthreads();

    const float* kp = k + (size_t)(b * N_ + t) * D_ + h * HD_;
    float dot = 0.f;
#pragma unroll
    for (int i = 0; i < HD_; ++i) dot += qrow[i] * kp[i];
    dot *= 0.125f;   // 1/sqrt(64)

    int pr = prio[((size_t)b * N_ + qi) * N_ + t];
    float bias = 0.f;
    bool adj = (t == qi);
    if (pr >= 0) {
        int e = (pr >= E_) ? pr - E_ : pr;
        bias = eb[((size_t)b * E_ + e) * H_ + h];
        adj = true;
    }
    float s = dot + bias;
    bool ok = adj && (nm[b * N_ + qi] != 0.f) && (nm[b * N_ + t] != 0.f);
    s = ok ? s : NEG_;

    // max reduce
    red[t] = s; __syncthreads();
    for (int off = 128; off > 0; off >>= 1) { if (t < off) red[t] = fmaxf(red[t], red[t + off]); __syncthreads(); }
    float m = red[0]; __syncthreads();

    float p = __expf(s - m);
    ps[t] = p; red[t] = p; __syncthreads();
    for (int off = 128; off > 0; off >>= 1) { if (t < off) red[t] += red[t + off]; __syncthreads(); }
    float sum = red[0];
    float inv = (sum > 0.f) ? 1.f / sum : 0.f;
    __syncthreads();

    // PV: thread t -> d = t&63, key-group kg = t>>6 (4 groups of 64 keys)
    int d = t & 63, kg = t >> 6;
    const float* vp = v + (size_t)(b * N_) * D_ + h * HD_ + d;
    float acc = 0.f;
    for (int kk = kg * 64; kk < kg * 64 + 64; ++kk)
        acc += ps[kk] * vp[(size_t)kk * D_];
    red[t] = acc; __syncthreads();
    if (t < 64) {
        float o = (red[t] + red[t + 64] + red[t + 128] + red[t + 192]) * inv;
        out[(size_t)(b * N_ + qi) * D_ + h * HD_ + t] = o;
    }
}

// ---------------- small elementwise kernels ----------------------------------
__global__ void initout_kernel(const float* __restrict__ x2, const float* __restrict__ b2,
                               float* __restrict__ out) {
    int idx = blockIdx.x * 256 + threadIdx.x;
    out[idx] = x2[idx] + b2[idx & (D_ - 1)];
}
__global__ void mask_kernel(const float* __restrict__ nm, float* __restrict__ out) {
    int idx = blockIdx.x * 256 + threadIdx.x;
    out[idx] *= nm[idx >> 10];
}

extern "C" void kernel_launch(void* const* d_in, const int* in_sizes, int n_in,
                              void* d_out, int out_size, void* d_ws, size_t ws_size,
                              hipStream_t stream) {
    const float* x     = (const float*)d_in[0];
    const float* nm    = (const float*)d_in[1];
    const int*   edges = (const int*)d_in[2];
    const float* emask = (const float*)d_in[3];
    const float* remb  = (const float*)d_in[4];
    const float* ln_g  = (const float*)d_in[5];
    const float* ln_b  = (const float*)d_in[6];
    const float* Wq = (const float*)d_in[7];  const float* bq = (const float*)d_in[8];
    const float* Wk = (const float*)d_in[9];  const float* bk = (const float*)d_in[10];
    const float* Wv = (const float*)d_in[11]; const float* bv = (const float*)d_in[12];
    const float* We = (const float*)d_in[13]; const float* be = (const float*)d_in[14];
    const float* Wo = (const float*)d_in[15]; const float* bo = (const float*)d_in[16];
    const float* ff_g = (const float*)d_in[17]; const float* ff_b = (const float*)d_in[18];
    const float* W1 = (const float*)d_in[19]; const float* b1 = (const float*)d_in[20];
    const float* W2 = (const float*)d_in[21]; const float* b2 = (const float*)d_in[22];
    float* out = (float*)d_out;

    // workspace layout (172 MB total, buffers reused):
    char* ws = (char*)d_ws;
    int*   prio = (int*)ws;                          //   0..8 MB  [B,N,N] int32
    float* eb   = (float*)(ws + (8ll  << 20));       //   8..9 MB  [B,E,H]
    float* xn   = (float*)(ws + (12ll << 20));       //  12..44 MB (reused: attn_out)
    float* qb   = (float*)(ws + (44ll << 20));       //  44..76 MB (reused: ffn mid)
    float* kb   = (float*)(ws + (76ll << 20));       //  76..108MB (reused: hn)
    float* vb   = (float*)(ws + (108ll << 20));      // 108..140MB
    float* x2   = (float*)(ws + (140ll << 20));      // 140..172MB
    float* mid  = qb;
    float* hn   = kb;

    const int M = B_ * N_;                           // 8192
    dim3 gg(D_ / BN, M / BM);                        // (16,128)

    hipMemsetAsync(prio, 0xFF, (size_t)B_ * N_ * N_ * sizeof(int), stream);
    eb_kernel<<<(B_ * E_ * H_ + 255) / 256, 256, 0, stream>>>(remb, We, be, eb);
    scatter_kernel<<<(B_ * E_ + 255) / 256, 256, 0, stream>>>(edges, emask, prio);

    ln_kernel<<<M, 256, 0, stream>>>(x, ln_g, ln_b, xn);
    gemm_kernel<0><<<gg, 256, 0, stream>>>(xn, Wq, bq, nullptr, qb, M, D_, D_, D_, D_, D_);
    gemm_kernel<0><<<gg, 256, 0, stream>>>(xn, Wk, bk, nullptr, kb, M, D_, D_, D_, D_, D_);
    gemm_kernel<0><<<gg, 256, 0, stream>>>(xn, Wv, bv, nullptr, vb, M, D_, D_, D_, D_, D_);

    attn_kernel<<<B_ * H_ * N_, 256, 0, stream>>>(qb, kb, vb, prio, eb, nm, xn);

    gemm_kernel<1><<<gg, 256, 0, stream>>>(xn, Wo, bo, x, x2, M, D_, D_, D_, D_, D_);
    ln_kernel<<<M, 256, 0, stream>>>(x2, ff_g, ff_b, hn);

    initout_kernel<<<(M * D_) / 256, 256, 0, stream>>>(x2, b2, out);
    for (int c = 0; c < 4; ++c) {
        gemm_kernel<2><<<gg, 256, 0, stream>>>(hn, W1 + c * 1024, b1 + c * 1024, nullptr,
                                               mid, M, D_, D_, D_, 4 * D_, D_);
        gemm_kernel<3><<<gg, 256, 0, stream>>>(mid, W2 + (size_t)c * 1024 * D_, nullptr, nullptr,
                                               out, M, D_, D_, D_, D_, D_);
    }
    mask_kernel<<<(M * D_) / 256, 256, 0, stream>>>(nm, out);
}

// Round 3
// 669.753 us; speedup vs baseline: 6.4736x; 6.4736x over previous
//
#include <hip/hip_runtime.h>
#include <math.h>

#define B_  32
#define N_  256
#define D_  1024
#define H_  16
#define E_  512
#define ED_ 256
#define HD_ 64
#define NEG_ (-3.4028234663852886e38f)

typedef __attribute__((ext_vector_type(8))) short short8;
typedef __attribute__((ext_vector_type(4))) float f32x4;
typedef unsigned short ushort_t;
typedef unsigned int uint_t;

union U16x8 { uint4 u4; ushort_t s[8]; };

static __device__ __forceinline__ ushort_t f2bf(float f) {
    uint_t u = __builtin_bit_cast(uint_t, f);
    u = (u + 0x7fff + ((u >> 16) & 1)) >> 16;
    return (ushort_t)u;
}
static __device__ __forceinline__ float bf2f(ushort_t s) {
    uint_t u = ((uint_t)s) << 16;
    return __builtin_bit_cast(float, u);
}

// async global->LDS, 16 bytes per lane (m97 pattern)
static __device__ __forceinline__ void gload_lds16(const void* g, void* l) {
    __builtin_amdgcn_global_load_lds(
        (const __attribute__((address_space(1))) unsigned int*)g,
        (__attribute__((address_space(3))) unsigned int*)l, 16, 0, 0);
}

// ---------------- LayerNorm: fp32 in -> bf16 out -----------------------------
__global__ __launch_bounds__(256) void ln_bf16_kernel(const float* __restrict__ x,
                                                      const float* __restrict__ g,
                                                      const float* __restrict__ b,
                                                      ushort_t* __restrict__ out) {
    int row = blockIdx.x;
    const float* xr = x + (size_t)row * D_;
    ushort_t* yr = out + (size_t)row * D_;
    __shared__ float red[256];
    int t = threadIdx.x;
    float vals[4];
    float s = 0.f;
#pragma unroll
    for (int i = 0; i < 4; ++i) { vals[i] = xr[t + i * 256]; s += vals[i]; }
    red[t] = s; __syncthreads();
    for (int off = 128; off > 0; off >>= 1) { if (t < off) red[t] += red[t + off]; __syncthreads(); }
    float mean = red[0] * (1.f / D_);
    __syncthreads();
    float vs = 0.f;
#pragma unroll
    for (int i = 0; i < 4; ++i) { float d = vals[i] - mean; vs += d * d; }
    red[t] = vs; __syncthreads();
    for (int off = 128; off > 0; off >>= 1) { if (t < off) red[t] += red[t + off]; __syncthreads(); }
    float rstd = 1.f / sqrtf(red[0] * (1.f / D_) + 1e-5f);
#pragma unroll
    for (int i = 0; i < 4; ++i) {
        int c = t + i * 256;
        yr[c] = f2bf((vals[i] - mean) * rstd * g[c] + b[c]);
    }
}

// ---------------- weight transpose+convert: in[K][N] f32 -> out[N][K] bf16 ---
__global__ __launch_bounds__(256) void transpose_bf16_kernel(const float* __restrict__ in,
                                                             ushort_t* __restrict__ out,
                                                             int K, int N) {
    __shared__ float tile[32][33];
    int n0 = blockIdx.x * 32, k0 = blockIdx.y * 32;
    int tx = threadIdx.x & 31, ty = threadIdx.x >> 5;   // ty 0..7
#pragma unroll
    for (int r = 0; r < 4; ++r)
        tile[ty + r * 8][tx] = in[(size_t)(k0 + ty + r * 8) * N + n0 + tx];
    __syncthreads();
#pragma unroll
    for (int r = 0; r < 4; ++r)
        out[(size_t)(n0 + ty + r * 8) * K + k0 + tx] = f2bf(tile[tx][ty + r * 8]);
}

// ---------------- edge-bias projection: eb[b,e,h] ----------------------------
__global__ __launch_bounds__(256) void eb_kernel(const float* __restrict__ re,
                                                 const float* __restrict__ We,
                                                 const float* __restrict__ be,
                                                 float* __restrict__ eb) {
    __shared__ float rs[16 * 256];
    __shared__ float wl[256 * 16];
    int t = threadIdx.x;
    int be0 = blockIdx.x * 16;     // base (b*E+e)
#pragma unroll
    for (int i = 0; i < 16; ++i) wl[t + i * 256] = We[t + i * 256];
#pragma unroll
    for (int i = 0; i < 16; ++i) rs[t + i * 256] = re[(size_t)be0 * 256 + t + i * 256];
    __syncthreads();
    int el = t >> 4, h = t & 15;
    float s = be[h];
#pragma unroll 8
    for (int i = 0; i < 256; ++i) s += rs[el * 256 + i] * wl[i * 16 + h];
    eb[(size_t)(be0 + el) * 16 + h] = s;
}

// ---------------- edge scatter: last-writer-wins priority table --------------
// forward (src,dst) -> prio e ; reverse (dst,src) -> prio E+e (reverse scatter
// runs after forward in the reference, so any reverse beats any forward).
__global__ void scatter_kernel(const int* __restrict__ edges, const float* __restrict__ emask,
                               int* __restrict__ prio) {
    int idx = blockIdx.x * blockDim.x + threadIdx.x;   // b*E + e
    if (idx >= B_ * E_) return;
    if (emask[idx] == 0.f) return;
    int b = idx / E_, e = idx % E_;
    int s = edges[2 * idx], d = edges[2 * idx + 1];
    s = min(max(s, 0), N_ - 1);
    d = min(max(d, 0), N_ - 1);
    int* base = prio + (size_t)b * N_ * N_;
    atomicMax(&base[s * N_ + d], e);
    atomicMax(&base[d * N_ + s], e + E_);
}

// ---------------- bf16 MFMA GEMM: C[M,N] = A[M,K] * BT[N,K]^T ---------------
// MODE 0: +bias -> bf16   1: +bias+res -> f32   2: silu(+bias) -> bf16
// MODE 3: +bias+res, *nm[row] -> f32
template<int MODE>
__global__ __launch_bounds__(256) void gemm_bf16(
    const ushort_t* __restrict__ A, const ushort_t* __restrict__ BT,
    const float* __restrict__ bias, const float* __restrict__ res,
    const float* __restrict__ nm, void* __restrict__ Cout,
    int M, int N, int K)
{
    __shared__ ushort_t As[128 * 32];
    __shared__ ushort_t Bs[128 * 32];
    int t = threadIdx.x;
    int lane = t & 63, c = lane & 15, quad = lane >> 4;
    int w = t >> 6;
    int wr = (w >> 1) * 64, wc = (w & 1) * 64;
    int row0 = blockIdx.y * 128, col0 = blockIdx.x * 128;
    const ushort_t* Ag = A + (size_t)row0 * K;
    const ushort_t* Bg = BT + (size_t)col0 * K;
    int srow = t >> 2, scol = (t & 3) * 8;

    f32x4 acc[4][4];
    f32x4 z = {0.f, 0.f, 0.f, 0.f};
#pragma unroll
    for (int i = 0; i < 4; ++i)
#pragma unroll
        for (int j = 0; j < 4; ++j) acc[i][j] = z;

    for (int k0 = 0; k0 < K; k0 += 32) {
        gload_lds16(Ag + (size_t)srow * K + k0 + scol, (char*)As + t * 16);
        gload_lds16(Ag + (size_t)(64 + srow) * K + k0 + scol, (char*)As + 4096 + t * 16);
        gload_lds16(Bg + (size_t)srow * K + k0 + scol, (char*)Bs + t * 16);
        gload_lds16(Bg + (size_t)(64 + srow) * K + k0 + scol, (char*)Bs + 4096 + t * 16);
        __syncthreads();
        short8 af[4], bf[4];
#pragma unroll
        for (int i = 0; i < 4; ++i)
            af[i] = *(const short8*)(const void*)(As + (wr + i * 16 + c) * 32 + quad * 8);
#pragma unroll
        for (int j = 0; j < 4; ++j)
            bf[j] = *(const short8*)(const void*)(Bs + (wc + j * 16 + c) * 32 + quad * 8);
#pragma unroll
        for (int i = 0; i < 4; ++i)
#pragma unroll
            for (int j = 0; j < 4; ++j)
                acc[i][j] = __builtin_amdgcn_mfma_f32_16x16x32_bf16(af[i], bf[j], acc[i][j], 0, 0, 0);
        __syncthreads();
    }

#pragma unroll
    for (int i = 0; i < 4; ++i) {
#pragma unroll
        for (int r = 0; r < 4; ++r) {
            int row = row0 + wr + i * 16 + quad * 4 + r;
#pragma unroll
            for (int j = 0; j < 4; ++j) {
                int col = col0 + wc + j * 16 + c;
                float v = acc[i][j][r] + bias[col];
                if (MODE == 0) {
                    ((ushort_t*)Cout)[(size_t)row * N + col] = f2bf(v);
                } else if (MODE == 1) {
                    ((float*)Cout)[(size_t)row * N + col] = v + res[(size_t)row * N + col];
                } else if (MODE == 2) {
                    v = v / (1.f + __expf(-v));
                    ((ushort_t*)Cout)[(size_t)row * N + col] = f2bf(v);
                } else { // 3
                    v = (v + res[(size_t)row * N + col]) * nm[row];
                    ((float*)Cout)[(size_t)row * N + col] = v;
                }
            }
        }
    }
}

// ---------------- MFMA attention: block = (b, h, q-tile of 64) ---------------
__global__ __launch_bounds__(256) void attn_mfma_kernel(
    const ushort_t* __restrict__ q, const ushort_t* __restrict__ k,
    const ushort_t* __restrict__ v, const int* __restrict__ prio,
    const float* __restrict__ eb, const float* __restrict__ nm,
    ushort_t* __restrict__ out)
{
    int bid = blockIdx.x;
    int qt = bid & 3, h = (bid >> 2) & 15, b = bid >> 6;
    int t = threadIdx.x;

    __shared__ ushort_t Qs[64 * 72];     //  9216 B
    __shared__ ushort_t Ks[256 * 72];    // 36864 B (reused as Ps[64*264])
    __shared__ ushort_t Vt[64 * 264];    // 33792 B  (transposed V: [d][key])

    // ---- staging ----
    int lr = t >> 3, lc = (t & 7) * 8;
    const ushort_t* qg = q + ((size_t)(b * N_ + qt * 64)) * D_ + h * HD_;
#pragma unroll
    for (int r = 0; r < 64; r += 32)
        *(uint4*)&Qs[(lr + r) * 72 + lc] = *(const uint4*)&qg[(size_t)(lr + r) * D_ + lc];
    const ushort_t* kg = k + ((size_t)(b * N_)) * D_ + h * HD_;
#pragma unroll
    for (int r = 0; r < 256; r += 32)
        *(uint4*)&Ks[(lr + r) * 72 + lc] = *(const uint4*)&kg[(size_t)(lr + r) * D_ + lc];
    const ushort_t* vg = v + ((size_t)(b * N_)) * D_ + h * HD_;
#pragma unroll
    for (int r = 0; r < 256; r += 32) {
        U16x8 uu; uu.u4 = *(const uint4*)&vg[(size_t)(lr + r) * D_ + lc];
#pragma unroll
        for (int i = 0; i < 8; ++i)
            Vt[(lc + i) * 264 + lr + r] = uu.s[i];
    }
    __syncthreads();

    int lane = t & 63, c = lane & 15, quad = lane >> 4;
    int w = t >> 6;

    // ---- QK^T ----
    f32x4 z = {0.f, 0.f, 0.f, 0.f};
    f32x4 acc[16];
#pragma unroll
    for (int j = 0; j < 16; ++j) acc[j] = z;
    short8 aq0 = *(const short8*)(const void*)(Qs + (w * 16 + c) * 72 + quad * 8);
    short8 aq1 = *(const short8*)(const void*)(Qs + (w * 16 + c) * 72 + 32 + quad * 8);
#pragma unroll
    for (int j = 0; j < 16; ++j) {
        short8 b0 = *(const short8*)(const void*)(Ks + (j * 16 + c) * 72 + quad * 8);
        short8 b1 = *(const short8*)(const void*)(Ks + (j * 16 + c) * 72 + 32 + quad * 8);
        acc[j] = __builtin_amdgcn_mfma_f32_16x16x32_bf16(aq0, b0, acc[j], 0, 0, 0);
        acc[j] = __builtin_amdgcn_mfma_f32_16x16x32_bf16(aq1, b1, acc[j], 0, 0, 0);
    }

    // ---- scores: scale + edge bias + mask (C-layout: row=quad*4+r, col=j*16+c)
    int qbase = qt * 64 + w * 16 + quad * 4;   // +r, within-batch node index
    float nmq[4];
#pragma unroll
    for (int r = 0; r < 4; ++r) nmq[r] = nm[b * N_ + qbase + r];
#pragma unroll
    for (int j = 0; j < 16; ++j) {
        int key = j * 16 + c;
        float nmk = nm[b * N_ + key];
        const int* prp = prio + ((size_t)(b * N_ + qbase)) * N_ + key;
#pragma unroll
        for (int r = 0; r < 4; ++r) {
            int pr = prp[(size_t)r * N_];
            float bias = 0.f;
            bool adj = (key == qbase + r);
            if (pr >= 0) {
                int e = (pr >= E_) ? pr - E_ : pr;
                bias = eb[((size_t)b * E_ + e) * H_ + h];
                adj = true;
            }
            float val = acc[j][r] * 0.125f + bias;
            bool ok = adj && (nmq[r] != 0.f) && (nmk != 0.f);
            acc[j][r] = ok ? val : NEG_;
        }
    }

    // ---- softmax per row (16 lanes of a quad hold one row across 16 tiles) --
    float inv[4];
#pragma unroll
    for (int r = 0; r < 4; ++r) {
        float m = acc[0][r];
#pragma unroll
        for (int j = 1; j < 16; ++j) m = fmaxf(m, acc[j][r]);
        m = fmaxf(m, __shfl_xor(m, 1));
        m = fmaxf(m, __shfl_xor(m, 2));
        m = fmaxf(m, __shfl_xor(m, 4));
        m = fmaxf(m, __shfl_xor(m, 8));
        float s = 0.f;
#pragma unroll
        for (int j = 0; j < 16; ++j) {
            float p = __expf(acc[j][r] - m);
            acc[j][r] = p;
            s += p;
        }
        s += __shfl_xor(s, 1);
        s += __shfl_xor(s, 2);
        s += __shfl_xor(s, 4);
        s += __shfl_xor(s, 8);
        inv[r] = 1.f / s;
    }

    __syncthreads();            // everyone done reading Ks
    ushort_t* Ps = Ks;          // reuse as P [64][264]
#pragma unroll
    for (int j = 0; j < 16; ++j)
#pragma unroll
        for (int r = 0; r < 4; ++r)
            Ps[(w * 16 + quad * 4 + r) * 264 + j * 16 + c] = f2bf(acc[j][r] * inv[r]);
    __syncthreads();

    // ---- PV ----
    f32x4 oc[4];
#pragma unroll
    for (int dt = 0; dt < 4; ++dt) oc[dt] = z;
#pragma unroll
    for (int k0 = 0; k0 < 256; k0 += 32) {
        short8 ap = *(const short8*)(const void*)(Ps + (w * 16 + c) * 264 + k0 + quad * 8);
#pragma unroll
        for (int dt = 0; dt < 4; ++dt) {
            short8 bv = *(const short8*)(const void*)(Vt + (dt * 16 + c) * 264 + k0 + quad * 8);
            oc[dt] = __builtin_amdgcn_mfma_f32_16x16x32_bf16(ap, bv, oc[dt], 0, 0, 0);
        }
    }
    ushort_t* og = out + ((size_t)(b * N_ + qt * 64 + w * 16)) * D_ + h * HD_;
#pragma unroll
    for (int dt = 0; dt < 4; ++dt)
#pragma unroll
        for (int r = 0; r < 4; ++r)
            og[(size_t)(quad * 4 + r) * D_ + dt * 16 + c] = f2bf(oc[dt][r]);
}

extern "C" void kernel_launch(void* const* d_in, const int* in_sizes, int n_in,
                              void* d_out, int out_size, void* d_ws, size_t ws_size,
                              hipStream_t stream) {
    const float* x     = (const float*)d_in[0];
    const float* nm    = (const float*)d_in[1];
    const int*   edges = (const int*)d_in[2];
    const float* emask = (const float*)d_in[3];
    const float* remb  = (const float*)d_in[4];
    const float* ln_g  = (const float*)d_in[5];
    const float* ln_b  = (const float*)d_in[6];
    const float* Wq = (const float*)d_in[7];  const float* bq = (const float*)d_in[8];
    const float* Wk = (const float*)d_in[9];  const float* bk = (const float*)d_in[10];
    const float* Wv = (const float*)d_in[11]; const float* bv = (const float*)d_in[12];
    const float* We = (const float*)d_in[13]; const float* be = (const float*)d_in[14];
    const float* Wo = (const float*)d_in[15]; const float* bo = (const float*)d_in[16];
    const float* ff_g = (const float*)d_in[17]; const float* ff_b = (const float*)d_in[18];
    const float* W1 = (const float*)d_in[19]; const float* b1 = (const float*)d_in[20];
    const float* W2 = (const float*)d_in[21]; const float* b2 = (const float*)d_in[22];
    float* out = (float*)d_out;

    char* ws = (char*)d_ws;
    const size_t MB = 1ll << 20;
    int*      prio = (int*)ws;                       // 0..8 MB
    float*    ebuf = (float*)(ws + 8 * MB);          // 8..9 MB
    ushort_t* xn   = (ushort_t*)(ws + 9 * MB);       // 9..25 MB (reused: attn_out)
    float*    x2   = (float*)(ws + 25 * MB);         // 25..57 MB
    ushort_t* hn   = (ushort_t*)(ws + 57 * MB);      // 57..73 MB
    ushort_t* qb   = (ushort_t*)(ws + 73 * MB);      // 73..89 MB
    ushort_t* kb   = (ushort_t*)(ws + 89 * MB);      // 89..105 MB
    ushort_t* vb   = (ushort_t*)(ws + 105 * MB);     // 105..121 MB
    ushort_t* mid  = qb;                             // 73..137 MB (qkv reused)
    ushort_t* WqT  = (ushort_t*)(ws + 137 * MB);
    ushort_t* WkT  = (ushort_t*)(ws + 139 * MB);
    ushort_t* WvT  = (ushort_t*)(ws + 141 * MB);
    ushort_t* WoT  = (ushort_t*)(ws + 143 * MB);
    ushort_t* W1T  = (ushort_t*)(ws + 145 * MB);     // [4096][1024] -> 8MB
    ushort_t* W2T  = (ushort_t*)(ws + 153 * MB);     // [1024][4096] -> 8MB
    ushort_t* aout = xn;

    const int M = B_ * N_;   // 8192

    (void)hipMemsetAsync(prio, 0xFF, (size_t)B_ * N_ * N_ * sizeof(int), stream);
    eb_kernel<<<B_ * E_ / 16, 256, 0, stream>>>(remb, We, be, ebuf);
    scatter_kernel<<<(B_ * E_ + 255) / 256, 256, 0, stream>>>(edges, emask, prio);

    transpose_bf16_kernel<<<dim3(32, 32), 256, 0, stream>>>(Wq, WqT, D_, D_);
    transpose_bf16_kernel<<<dim3(32, 32), 256, 0, stream>>>(Wk, WkT, D_, D_);
    transpose_bf16_kernel<<<dim3(32, 32), 256, 0, stream>>>(Wv, WvT, D_, D_);
    transpose_bf16_kernel<<<dim3(32, 32), 256, 0, stream>>>(Wo, WoT, D_, D_);
    transpose_bf16_kernel<<<dim3(128, 32), 256, 0, stream>>>(W1, W1T, D_, 4 * D_);
    transpose_bf16_kernel<<<dim3(32, 128), 256, 0, stream>>>(W2, W2T, 4 * D_, D_);

    ln_bf16_kernel<<<M, 256, 0, stream>>>(x, ln_g, ln_b, xn);

    gemm_bf16<0><<<dim3(8, 64), 256, 0, stream>>>(xn, WqT, bq, nullptr, nullptr, qb, M, D_, D_);
    gemm_bf16<0><<<dim3(8, 64), 256, 0, stream>>>(xn, WkT, bk, nullptr, nullptr, kb, M, D_, D_);
    gemm_bf16<0><<<dim3(8, 64), 256, 0, stream>>>(xn, WvT, bv, nullptr, nullptr, vb, M, D_, D_);

    attn_mfma_kernel<<<B_ * H_ * 4, 256, 0, stream>>>(qb, kb, vb, prio, ebuf, nm, aout);

    gemm_bf16<1><<<dim3(8, 64), 256, 0, stream>>>(aout, WoT, bo, x, nullptr, x2, M, D_, D_);
    ln_bf16_kernel<<<M, 256, 0, stream>>>(x2, ff_g, ff_b, hn);

    gemm_bf16<2><<<dim3(32, 64), 256, 0, stream>>>(hn, W1T, b1, nullptr, nullptr, mid, M, 4 * D_, D_);
    gemm_bf16<3><<<dim3(8, 64), 256, 0, stream>>>(mid, W2T, b2, x2, nm, out, M, D_, 4 * D_);
}

// Round 4
// 652.427 us; speedup vs baseline: 6.6455x; 1.0266x over previous
//
#include <hip/hip_runtime.h>
#include <math.h>

#define B_  32
#define N_  256
#define D_  1024
#define H_  16
#define E_  512
#define ED_ 256
#define HD_ 64
#define QS_ 3072                  // merged qkv row stride
#define NEG_ (-3.4028234663852886e38f)

typedef __attribute__((ext_vector_type(8))) short short8;
typedef __attribute__((ext_vector_type(4))) float f32x4;
typedef unsigned short ushort_t;
typedef unsigned int uint_t;

union U16x8 { uint4 u4; ushort_t s[8]; };

static __device__ __forceinline__ ushort_t f2bf(float f) {
    uint_t u = __builtin_bit_cast(uint_t, f);
    u = (u + 0x7fff + ((u >> 16) & 1)) >> 16;
    return (ushort_t)u;
}

// async global->LDS, 16 bytes per lane (m97 pattern)
static __device__ __forceinline__ void gload_lds16(const void* g, void* l) {
    __builtin_amdgcn_global_load_lds(
        (const __attribute__((address_space(1))) unsigned int*)g,
        (__attribute__((address_space(3))) unsigned int*)l, 16, 0, 0);
}

// ---------------- LayerNorm: fp32 in -> bf16 out -----------------------------
__global__ __launch_bounds__(256) void ln_bf16_kernel(const float* __restrict__ x,
                                                      const float* __restrict__ g,
                                                      const float* __restrict__ b,
                                                      ushort_t* __restrict__ out) {
    int row = blockIdx.x;
    const float* xr = x + (size_t)row * D_;
    ushort_t* yr = out + (size_t)row * D_;
    __shared__ float red[256];
    int t = threadIdx.x;
    float vals[4];
    float s = 0.f;
#pragma unroll
    for (int i = 0; i < 4; ++i) { vals[i] = xr[t + i * 256]; s += vals[i]; }
    red[t] = s; __syncthreads();
    for (int off = 128; off > 0; off >>= 1) { if (t < off) red[t] += red[t + off]; __syncthreads(); }
    float mean = red[0] * (1.f / D_);
    __syncthreads();
    float vs = 0.f;
#pragma unroll
    for (int i = 0; i < 4; ++i) { float d = vals[i] - mean; vs += d * d; }
    red[t] = vs; __syncthreads();
    for (int off = 128; off > 0; off >>= 1) { if (t < off) red[t] += red[t + off]; __syncthreads(); }
    float rstd = 1.f / sqrtf(red[0] * (1.f / D_) + 1e-5f);
#pragma unroll
    for (int i = 0; i < 4; ++i) {
        int c = t + i * 256;
        yr[c] = f2bf((vals[i] - mean) * rstd * g[c] + b[c]);
    }
}

// ---------------- weight transpose+convert: in[K][N] f32 -> out[N][K] bf16 ---
__global__ __launch_bounds__(256) void transpose_bf16_kernel(const float* __restrict__ in,
                                                             ushort_t* __restrict__ out,
                                                             int K, int N) {
    __shared__ float tile[32][33];
    int n0 = blockIdx.x * 32, k0 = blockIdx.y * 32;
    int tx = threadIdx.x & 31, ty = threadIdx.x >> 5;   // ty 0..7
#pragma unroll
    for (int r = 0; r < 4; ++r)
        tile[ty + r * 8][tx] = in[(size_t)(k0 + ty + r * 8) * N + n0 + tx];
    __syncthreads();
#pragma unroll
    for (int r = 0; r < 4; ++r)
        out[(size_t)(n0 + ty + r * 8) * K + k0 + tx] = f2bf(tile[tx][ty + r * 8]);
}

// ---------------- concat bias [bq|bk|bv] -------------------------------------
__global__ void cbias_kernel(const float* __restrict__ bq, const float* __restrict__ bk,
                             const float* __restrict__ bv, float* __restrict__ cb) {
    int i = blockIdx.x * 256 + threadIdx.x;   // 3072
    float v = (i < 1024) ? bq[i] : ((i < 2048) ? bk[i - 1024] : bv[i - 2048]);
    cb[i] = v;
}

// ---------------- edge-bias projection: eb[b,e,h] ----------------------------
__global__ __launch_bounds__(256) void eb_kernel(const float* __restrict__ re,
                                                 const float* __restrict__ We,
                                                 const float* __restrict__ be,
                                                 float* __restrict__ eb) {
    __shared__ float rs[16 * 256];
    __shared__ float wl[256 * 16];
    int t = threadIdx.x;
    int be0 = blockIdx.x * 16;     // base (b*E+e)
#pragma unroll
    for (int i = 0; i < 16; ++i) wl[t + i * 256] = We[t + i * 256];
#pragma unroll
    for (int i = 0; i < 16; ++i) rs[t + i * 256] = re[(size_t)be0 * 256 + t + i * 256];
    __syncthreads();
    int el = t >> 4, h = t & 15;
    float s = be[h];
#pragma unroll 8
    for (int i = 0; i < 256; ++i) s += rs[el * 256 + i] * wl[i * 16 + h];
    eb[(size_t)(be0 + el) * 16 + h] = s;
}

// ---------------- edge scatter: last-writer-wins priority table --------------
// forward (src,dst) -> prio e ; reverse (dst,src) -> prio E+e (reverse scatter
// runs after forward in the reference, so any reverse beats any forward).
__global__ void scatter_kernel(const int* __restrict__ edges, const float* __restrict__ emask,
                               int* __restrict__ prio) {
    int idx = blockIdx.x * blockDim.x + threadIdx.x;   // b*E + e
    if (idx >= B_ * E_) return;
    if (emask[idx] == 0.f) return;
    int b = idx / E_, e = idx % E_;
    int s = edges[2 * idx], d = edges[2 * idx + 1];
    s = min(max(s, 0), N_ - 1);
    d = min(max(d, 0), N_ - 1);
    int* base = prio + (size_t)b * N_ * N_;
    atomicMax(&base[s * N_ + d], e);
    atomicMax(&base[d * N_ + s], e + E_);
}

// ---------------- bf16 MFMA GEMM: C[M,N] = A[M,K] * BT[N,K]^T ---------------
// LDS tile is XOR-swizzled: slot (r, sl) holds K-chunk s = sl ^ ((r>>1)&3),
// so the 16-lane ds_read_b128 fragment fetch covers all 8 four-bank groups
// exactly twice (2-way = free, m136). global_load_lds dest stays lane*16.
// MODE 0: +bias -> bf16   1: +bias+res -> f32   2: silu(+bias) -> bf16
// MODE 3: +bias+res, *nm[row] -> f32
template<int MODE>
__global__ __launch_bounds__(256) void gemm_bf16(
    const ushort_t* __restrict__ A, const ushort_t* __restrict__ BT,
    const float* __restrict__ bias, const float* __restrict__ res,
    const float* __restrict__ nm, void* __restrict__ Cout,
    int M, int N, int K)
{
    __shared__ ushort_t As[128 * 32];
    __shared__ ushort_t Bs[128 * 32];
    int t = threadIdx.x;
    int lane = t & 63, c = lane & 15, quad = lane >> 4;
    int w = t >> 6;
    int wr = (w >> 1) * 64, wc = (w & 1) * 64;
    int row0 = blockIdx.y * 128, col0 = blockIdx.x * 128;
    const ushort_t* Ag = A + (size_t)row0 * K;
    const ushort_t* Bg = BT + (size_t)col0 * K;
    int r0 = t >> 2;                               // staging row 0..63
    int sl = t & 3;
    int sc = (sl ^ ((r0 >> 1) & 3)) * 8;           // swizzled source chunk

    f32x4 acc[4][4];
    f32x4 z = {0.f, 0.f, 0.f, 0.f};
#pragma unroll
    for (int i = 0; i < 4; ++i)
#pragma unroll
        for (int j = 0; j < 4; ++j) acc[i][j] = z;

    for (int k0 = 0; k0 < K; k0 += 32) {
        gload_lds16(Ag + (size_t)r0 * K + k0 + sc, (char*)As + t * 16);
        gload_lds16(Ag + (size_t)(64 + r0) * K + k0 + sc, (char*)As + 4096 + t * 16);
        gload_lds16(Bg + (size_t)r0 * K + k0 + sc, (char*)Bs + t * 16);
        gload_lds16(Bg + (size_t)(64 + r0) * K + k0 + sc, (char*)Bs + 4096 + t * 16);
        __syncthreads();
        short8 af[4], bf[4];
#pragma unroll
        for (int i = 0; i < 4; ++i) {
            int rr = wr + i * 16 + c;
            int x = (quad ^ ((rr >> 1) & 3)) * 8;
            af[i] = *(const short8*)(const void*)(As + rr * 32 + x);
        }
#pragma unroll
        for (int j = 0; j < 4; ++j) {
            int rr = wc + j * 16 + c;
            int x = (quad ^ ((rr >> 1) & 3)) * 8;
            bf[j] = *(const short8*)(const void*)(Bs + rr * 32 + x);
        }
#pragma unroll
        for (int i = 0; i < 4; ++i)
#pragma unroll
            for (int j = 0; j < 4; ++j)
                acc[i][j] = __builtin_amdgcn_mfma_f32_16x16x32_bf16(af[i], bf[j], acc[i][j], 0, 0, 0);
        __syncthreads();
    }

#pragma unroll
    for (int i = 0; i < 4; ++i) {
#pragma unroll
        for (int r = 0; r < 4; ++r) {
            int row = row0 + wr + i * 16 + quad * 4 + r;
#pragma unroll
            for (int j = 0; j < 4; ++j) {
                int col = col0 + wc + j * 16 + c;
                float v = acc[i][j][r] + bias[col];
                if (MODE == 0) {
                    ((ushort_t*)Cout)[(size_t)row * N + col] = f2bf(v);
                } else if (MODE == 1) {
                    ((float*)Cout)[(size_t)row * N + col] = v + res[(size_t)row * N + col];
                } else if (MODE == 2) {
                    v = v / (1.f + __expf(-v));
                    ((ushort_t*)Cout)[(size_t)row * N + col] = f2bf(v);
                } else { // 3
                    v = (v + res[(size_t)row * N + col]) * nm[row];
                    ((float*)Cout)[(size_t)row * N + col] = v;
                }
            }
        }
    }
}

// ---------------- MFMA attention: block = (b, h, q-tile of 64) ---------------
// q/k/v live in one merged buffer with row stride QS_ (q:+0, k:+1024, v:+2048).
__global__ __launch_bounds__(256) void attn_mfma_kernel(
    const ushort_t* __restrict__ qkv, const int* __restrict__ prio,
    const float* __restrict__ eb, const float* __restrict__ nm,
    ushort_t* __restrict__ out)
{
    int bid = blockIdx.x;
    int qt = bid & 3, h = (bid >> 2) & 15, b = bid >> 6;
    int t = threadIdx.x;

    __shared__ ushort_t Qs[64 * 72];     //  9216 B
    __shared__ ushort_t Ks[256 * 72];    // 36864 B (reused as Ps[64*264])
    __shared__ ushort_t Vt[64 * 264];    // 33792 B  (transposed V: [d][key])

    // ---- staging ----
    int lr = t >> 3, lc = (t & 7) * 8;
    const ushort_t* qg = qkv + ((size_t)(b * N_ + qt * 64)) * QS_ + h * HD_;
#pragma unroll
    for (int r = 0; r < 64; r += 32)
        *(uint4*)&Qs[(lr + r) * 72 + lc] = *(const uint4*)&qg[(size_t)(lr + r) * QS_ + lc];
    const ushort_t* kg = qkv + ((size_t)(b * N_)) * QS_ + 1024 + h * HD_;
#pragma unroll
    for (int r = 0; r < 256; r += 32)
        *(uint4*)&Ks[(lr + r) * 72 + lc] = *(const uint4*)&kg[(size_t)(lr + r) * QS_ + lc];
    const ushort_t* vg = qkv + ((size_t)(b * N_)) * QS_ + 2048 + h * HD_;
#pragma unroll
    for (int r = 0; r < 256; r += 32) {
        U16x8 uu; uu.u4 = *(const uint4*)&vg[(size_t)(lr + r) * QS_ + lc];
#pragma unroll
        for (int i = 0; i < 8; ++i)
            Vt[(lc + i) * 264 + lr + r] = uu.s[i];
    }
    __syncthreads();

    int lane = t & 63, c = lane & 15, quad = lane >> 4;
    int w = t >> 6;

    // ---- QK^T ----
    f32x4 z = {0.f, 0.f, 0.f, 0.f};
    f32x4 acc[16];
#pragma unroll
    for (int j = 0; j < 16; ++j) acc[j] = z;
    short8 aq0 = *(const short8*)(const void*)(Qs + (w * 16 + c) * 72 + quad * 8);
    short8 aq1 = *(const short8*)(const void*)(Qs + (w * 16 + c) * 72 + 32 + quad * 8);
#pragma unroll
    for (int j = 0; j < 16; ++j) {
        short8 b0 = *(const short8*)(const void*)(Ks + (j * 16 + c) * 72 + quad * 8);
        short8 b1 = *(const short8*)(const void*)(Ks + (j * 16 + c) * 72 + 32 + quad * 8);
        acc[j] = __builtin_amdgcn_mfma_f32_16x16x32_bf16(aq0, b0, acc[j], 0, 0, 0);
        acc[j] = __builtin_amdgcn_mfma_f32_16x16x32_bf16(aq1, b1, acc[j], 0, 0, 0);
    }

    // ---- scores: scale + edge bias + mask (C-layout: row=quad*4+r, col=j*16+c)
    int qbase = qt * 64 + w * 16 + quad * 4;   // +r, within-batch node index
    float nmq[4];
#pragma unroll
    for (int r = 0; r < 4; ++r) nmq[r] = nm[b * N_ + qbase + r];
#pragma unroll
    for (int j = 0; j < 16; ++j) {
        int key = j * 16 + c;
        float nmk = nm[b * N_ + key];
        const int* prp = prio + ((size_t)(b * N_ + qbase)) * N_ + key;
#pragma unroll
        for (int r = 0; r < 4; ++r) {
            int pr = prp[(size_t)r * N_];
            float bias = 0.f;
            bool adj = (key == qbase + r);
            if (pr >= 0) {
                int e = (pr >= E_) ? pr - E_ : pr;
                bias = eb[((size_t)b * E_ + e) * H_ + h];
                adj = true;
            }
            float val = acc[j][r] * 0.125f + bias;
            bool ok = adj && (nmq[r] != 0.f) && (nmk != 0.f);
            acc[j][r] = ok ? val : NEG_;
        }
    }

    // ---- softmax per row (16 lanes of a quad hold one row across 16 tiles) --
    float inv[4];
#pragma unroll
    for (int r = 0; r < 4; ++r) {
        float m = acc[0][r];
#pragma unroll
        for (int j = 1; j < 16; ++j) m = fmaxf(m, acc[j][r]);
        m = fmaxf(m, __shfl_xor(m, 1));
        m = fmaxf(m, __shfl_xor(m, 2));
        m = fmaxf(m, __shfl_xor(m, 4));
        m = fmaxf(m, __shfl_xor(m, 8));
        float s = 0.f;
#pragma unroll
        for (int j = 0; j < 16; ++j) {
            float p = __expf(acc[j][r] - m);
            acc[j][r] = p;
            s += p;
        }
        s += __shfl_xor(s, 1);
        s += __shfl_xor(s, 2);
        s += __shfl_xor(s, 4);
        s += __shfl_xor(s, 8);
        inv[r] = 1.f / s;
    }

    __syncthreads();            // everyone done reading Ks
    ushort_t* Ps = Ks;          // reuse as P [64][264]
#pragma unroll
    for (int j = 0; j < 16; ++j)
#pragma unroll
        for (int r = 0; r < 4; ++r)
            Ps[(w * 16 + quad * 4 + r) * 264 + j * 16 + c] = f2bf(acc[j][r] * inv[r]);
    __syncthreads();

    // ---- PV ----
    f32x4 oc[4];
#pragma unroll
    for (int dt = 0; dt < 4; ++dt) oc[dt] = z;
#pragma unroll
    for (int k0 = 0; k0 < 256; k0 += 32) {
        short8 ap = *(const short8*)(const void*)(Ps + (w * 16 + c) * 264 + k0 + quad * 8);
#pragma unroll
        for (int dt = 0; dt < 4; ++dt) {
            short8 bv = *(const short8*)(const void*)(Vt + (dt * 16 + c) * 264 + k0 + quad * 8);
            oc[dt] = __builtin_amdgcn_mfma_f32_16x16x32_bf16(ap, bv, oc[dt], 0, 0, 0);
        }
    }
    ushort_t* og = out + ((size_t)(b * N_ + qt * 64 + w * 16)) * D_ + h * HD_;
#pragma unroll
    for (int dt = 0; dt < 4; ++dt)
#pragma unroll
        for (int r = 0; r < 4; ++r)
            og[(size_t)(quad * 4 + r) * D_ + dt * 16 + c] = f2bf(oc[dt][r]);
}

extern "C" void kernel_launch(void* const* d_in, const int* in_sizes, int n_in,
                              void* d_out, int out_size, void* d_ws, size_t ws_size,
                              hipStream_t stream) {
    const float* x     = (const float*)d_in[0];
    const float* nm    = (const float*)d_in[1];
    const int*   edges = (const int*)d_in[2];
    const float* emask = (const float*)d_in[3];
    const float* remb  = (const float*)d_in[4];
    const float* ln_g  = (const float*)d_in[5];
    const float* ln_b  = (const float*)d_in[6];
    const float* Wq = (const float*)d_in[7];  const float* bq = (const float*)d_in[8];
    const float* Wk = (const float*)d_in[9];  const float* bk = (const float*)d_in[10];
    const float* Wv = (const float*)d_in[11]; const float* bv = (const float*)d_in[12];
    const float* We = (const float*)d_in[13]; const float* be = (const float*)d_in[14];
    const float* Wo = (const float*)d_in[15]; const float* bo = (const float*)d_in[16];
    const float* ff_g = (const float*)d_in[17]; const float* ff_b = (const float*)d_in[18];
    const float* W1 = (const float*)d_in[19]; const float* b1 = (const float*)d_in[20];
    const float* W2 = (const float*)d_in[21]; const float* b2 = (const float*)d_in[22];
    float* out = (float*)d_out;

    char* ws = (char*)d_ws;
    const size_t MB = 1ll << 20;
    int*      prio = (int*)ws;                       // 0..8 MB
    float*    ebuf = (float*)(ws + 8 * MB);          // 8..9 MB
    ushort_t* xn   = (ushort_t*)(ws + 9 * MB);       // 9..25 MB (reused: attn_out)
    float*    x2   = (float*)(ws + 25 * MB);         // 25..57 MB
    ushort_t* hn   = (ushort_t*)(ws + 57 * MB);      // 57..73 MB
    ushort_t* qkv  = (ushort_t*)(ws + 73 * MB);      // 73..121 MB [8192][3072]
    ushort_t* mid  = qkv;                            // 73..137 MB (qkv dead by then)
    ushort_t* qkvT = (ushort_t*)(ws + 137 * MB);     // 137..143 MB [3072][1024]
    ushort_t* WoT  = (ushort_t*)(ws + 143 * MB);     // 143..145 MB
    ushort_t* W1T  = (ushort_t*)(ws + 145 * MB);     // 145..153 MB [4096][1024]
    ushort_t* W2T  = (ushort_t*)(ws + 153 * MB);     // 153..161 MB [1024][4096]
    float*    cb   = (float*)(ws + 161 * MB);        // 161..161.02 MB [3072]
    ushort_t* aout = xn;

    const int M = B_ * N_;   // 8192

    (void)hipMemsetAsync(prio, 0xFF, (size_t)B_ * N_ * N_ * sizeof(int), stream);
    eb_kernel<<<B_ * E_ / 16, 256, 0, stream>>>(remb, We, be, ebuf);
    scatter_kernel<<<(B_ * E_ + 255) / 256, 256, 0, stream>>>(edges, emask, prio);

    transpose_bf16_kernel<<<dim3(32, 32), 256, 0, stream>>>(Wq, qkvT, D_, D_);
    transpose_bf16_kernel<<<dim3(32, 32), 256, 0, stream>>>(Wk, qkvT + 1024 * 1024, D_, D_);
    transpose_bf16_kernel<<<dim3(32, 32), 256, 0, stream>>>(Wv, qkvT + 2 * 1024 * 1024, D_, D_);
    transpose_bf16_kernel<<<dim3(32, 32), 256, 0, stream>>>(Wo, WoT, D_, D_);
    transpose_bf16_kernel<<<dim3(128, 32), 256, 0, stream>>>(W1, W1T, D_, 4 * D_);
    transpose_bf16_kernel<<<dim3(32, 128), 256, 0, stream>>>(W2, W2T, 4 * D_, D_);
    cbias_kernel<<<12, 256, 0, stream>>>(bq, bk, bv, cb);

    ln_bf16_kernel<<<M, 256, 0, stream>>>(x, ln_g, ln_b, xn);

    gemm_bf16<0><<<dim3(24, 64), 256, 0, stream>>>(xn, qkvT, cb, nullptr, nullptr, qkv, M, QS_, D_);

    attn_mfma_kernel<<<B_ * H_ * 4, 256, 0, stream>>>(qkv, prio, ebuf, nm, aout);

    gemm_bf16<1><<<dim3(8, 64), 256, 0, stream>>>(aout, WoT, bo, x, nullptr, x2, M, D_, D_);
    ln_bf16_kernel<<<M, 256, 0, stream>>>(x2, ff_g, ff_b, hn);

    gemm_bf16<2><<<dim3(32, 64), 256, 0, stream>>>(hn, W1T, b1, nullptr, nullptr, mid, M, 4 * D_, D_);
    gemm_bf16<3><<<dim3(8, 64), 256, 0, stream>>>(mid, W2T, b2, x2, nm, out, M, D_, 4 * D_);
}

// Round 5
// 597.609 us; speedup vs baseline: 7.2551x; 1.0917x over previous
//
#include <hip/hip_runtime.h>
#include <math.h>

#define B_  32
#define N_  256
#define D_  1024
#define H_  16
#define E_  512
#define ED_ 256
#define HD_ 64
#define QS_ 3072                  // merged qkv row stride
#define NEG_ (-3.4028234663852886e38f)

typedef __attribute__((ext_vector_type(8))) short short8;
typedef __attribute__((ext_vector_type(4))) float f32x4;
typedef __attribute__((ext_vector_type(16))) float f32x16;
typedef unsigned short ushort_t;
typedef unsigned int uint_t;

union U16x8 { uint4 u4; ushort_t s[8]; };

static __device__ __forceinline__ ushort_t f2bf(float f) {
    uint_t u = __builtin_bit_cast(uint_t, f);
    u = (u + 0x7fff + ((u >> 16) & 1)) >> 16;
    return (ushort_t)u;
}

// async global->LDS, 16 bytes per lane (m97 pattern)
static __device__ __forceinline__ void gload_lds16(const void* g, void* l) {
    __builtin_amdgcn_global_load_lds(
        (const __attribute__((address_space(1))) unsigned int*)g,
        (__attribute__((address_space(3))) unsigned int*)l, 16, 0, 0);
}

// ---------------- LayerNorm: fp32 in -> bf16 out -----------------------------
__global__ __launch_bounds__(256) void ln_bf16_kernel(const float* __restrict__ x,
                                                      const float* __restrict__ g,
                                                      const float* __restrict__ b,
                                                      ushort_t* __restrict__ out) {
    int row = blockIdx.x;
    const float* xr = x + (size_t)row * D_;
    ushort_t* yr = out + (size_t)row * D_;
    __shared__ float red[256];
    int t = threadIdx.x;
    float vals[4];
    float s = 0.f;
#pragma unroll
    for (int i = 0; i < 4; ++i) { vals[i] = xr[t + i * 256]; s += vals[i]; }
    red[t] = s; __syncthreads();
    for (int off = 128; off > 0; off >>= 1) { if (t < off) red[t] += red[t + off]; __syncthreads(); }
    float mean = red[0] * (1.f / D_);
    __syncthreads();
    float vs = 0.f;
#pragma unroll
    for (int i = 0; i < 4; ++i) { float d = vals[i] - mean; vs += d * d; }
    red[t] = vs; __syncthreads();
    for (int off = 128; off > 0; off >>= 1) { if (t < off) red[t] += red[t + off]; __syncthreads(); }
    float rstd = 1.f / sqrtf(red[0] * (1.f / D_) + 1e-5f);
#pragma unroll
    for (int i = 0; i < 4; ++i) {
        int c = t + i * 256;
        yr[c] = f2bf((vals[i] - mean) * rstd * g[c] + b[c]);
    }
}

// ---------------- fused prep: all weight transposes + concat bias ------------
// ids [0,4096): Wq/Wk/Wv/Wo (1024 32x32 tiles each)
// ids [4096,8192): W1 (K=1024,N=4096)   ids [8192,12288): W2 (K=4096,N=1024)
// ids [12288,12300): cbias 3072 elems
__global__ __launch_bounds__(256) void prep_kernel(
    const float* __restrict__ Wq, const float* __restrict__ Wk,
    const float* __restrict__ Wv, const float* __restrict__ Wo,
    const float* __restrict__ W1, const float* __restrict__ W2,
    const float* __restrict__ bq, const float* __restrict__ bk,
    const float* __restrict__ bv,
    ushort_t* __restrict__ qkvT, ushort_t* __restrict__ WoT,
    ushort_t* __restrict__ W1T, ushort_t* __restrict__ W2T,
    float* __restrict__ cb)
{
    int id = blockIdx.x;
    if (id >= 12288) {
        int i = (id - 12288) * 256 + threadIdx.x;
        cb[i] = (i < 1024) ? bq[i] : ((i < 2048) ? bk[i - 1024] : bv[i - 2048]);
        return;
    }
    const float* in; ushort_t* outp; int K, N, tid;
    if (id < 4096) {
        int wsel = id >> 10; tid = id & 1023; K = D_; N = D_;
        in   = (wsel == 0) ? Wq : (wsel == 1) ? Wk : (wsel == 2) ? Wv : Wo;
        outp = (wsel == 0) ? qkvT : (wsel == 1) ? qkvT + 1024 * 1024
             : (wsel == 2) ? qkvT + 2 * 1024 * 1024 : WoT;
    } else if (id < 8192) { tid = id - 4096; K = D_; N = 4 * D_; in = W1; outp = W1T; }
    else                  { tid = id - 8192; K = 4 * D_; N = D_; in = W2; outp = W2T; }
    int tilesX = N >> 5;
    int n0 = (tid % tilesX) * 32, k0 = (tid / tilesX) * 32;

    __shared__ float tile[32][33];
    int tx = threadIdx.x & 31, ty = threadIdx.x >> 5;   // ty 0..7
#pragma unroll
    for (int r = 0; r < 4; ++r)
        tile[ty + r * 8][tx] = in[(size_t)(k0 + ty + r * 8) * N + n0 + tx];
    __syncthreads();
#pragma unroll
    for (int r = 0; r < 4; ++r)
        outp[(size_t)(n0 + ty + r * 8) * K + k0 + tx] = f2bf(tile[tx][ty + r * 8]);
}

// ---------------- edge-bias projection: eb[b,e,h] ----------------------------
__global__ __launch_bounds__(256) void eb_kernel(const float* __restrict__ re,
                                                 const float* __restrict__ We,
                                                 const float* __restrict__ be,
                                                 float* __restrict__ eb) {
    __shared__ float rs[16 * 256];
    __shared__ float wl[256 * 16];
    int t = threadIdx.x;
    int be0 = blockIdx.x * 16;     // base (b*E+e)
#pragma unroll
    for (int i = 0; i < 16; ++i) wl[t + i * 256] = We[t + i * 256];
#pragma unroll
    for (int i = 0; i < 16; ++i) rs[t + i * 256] = re[(size_t)be0 * 256 + t + i * 256];
    __syncthreads();
    int el = t >> 4, h = t & 15;
    float s = be[h];
#pragma unroll 8
    for (int i = 0; i < 256; ++i) s += rs[el * 256 + i] * wl[i * 16 + h];
    eb[(size_t)(be0 + el) * 16 + h] = s;
}

// ---------------- edge scatter: last-writer-wins priority table --------------
// forward (src,dst) -> prio e ; reverse (dst,src) -> prio E+e (reverse scatter
// runs after forward in the reference, so any reverse beats any forward).
__global__ void scatter_kernel(const int* __restrict__ edges, const float* __restrict__ emask,
                               int* __restrict__ prio) {
    int idx = blockIdx.x * blockDim.x + threadIdx.x;   // b*E + e
    if (idx >= B_ * E_) return;
    if (emask[idx] == 0.f) return;
    int b = idx / E_, e = idx % E_;
    int s = edges[2 * idx], d = edges[2 * idx + 1];
    s = min(max(s, 0), N_ - 1);
    d = min(max(d, 0), N_ - 1);
    int* base = prio + (size_t)b * N_ * N_;
    atomicMax(&base[s * N_ + d], e);
    atomicMax(&base[d * N_ + s], e + E_);
}

// ---------------- bf16 MFMA GEMM (32x32x16): C = A[M,K] * BT[N,K]^T ---------
// 128x128 block, 4 waves in 2x2, each wave 64x64 = 2x2 tiles of 32x32.
// LDS XOR-swizzled on the global source side (R4: conflicts -> 0).
// MODE 0: +bias -> bf16   1: +bias+res -> f32   2: silu(+bias) -> bf16
// MODE 3: +bias+res, *nm[row] -> f32
template<int MODE>
__global__ __launch_bounds__(256) void gemm_bf16(
    const ushort_t* __restrict__ A, const ushort_t* __restrict__ BT,
    const float* __restrict__ bias, const float* __restrict__ res,
    const float* __restrict__ nm, void* __restrict__ Cout,
    int M, int N, int K)
{
    __shared__ ushort_t As[128 * 32];
    __shared__ ushort_t Bs[128 * 32];
    int t = threadIdx.x;
    int lane = t & 63;
    int l31 = lane & 31, lh = lane >> 5;           // row/col in tile, k-half
    int w = t >> 6;
    int wr = (w >> 1) * 64, wc = (w & 1) * 64;
    int row0 = blockIdx.y * 128, col0 = blockIdx.x * 128;
    const ushort_t* Ag = A + (size_t)row0 * K;
    const ushort_t* Bg = BT + (size_t)col0 * K;
    int r0 = t >> 2;                               // staging row 0..63
    int sl = t & 3;
    int sc = (sl ^ ((r0 >> 1) & 3)) * 8;           // swizzled source chunk

    f32x16 acc[2][2];
#pragma unroll
    for (int i = 0; i < 2; ++i)
#pragma unroll
        for (int j = 0; j < 2; ++j)
#pragma unroll
            for (int r = 0; r < 16; ++r) acc[i][j][r] = 0.f;

    for (int k0 = 0; k0 < K; k0 += 32) {
        gload_lds16(Ag + (size_t)r0 * K + k0 + sc, (char*)As + t * 16);
        gload_lds16(Ag + (size_t)(64 + r0) * K + k0 + sc, (char*)As + 4096 + t * 16);
        gload_lds16(Bg + (size_t)r0 * K + k0 + sc, (char*)Bs + t * 16);
        gload_lds16(Bg + (size_t)(64 + r0) * K + k0 + sc, (char*)Bs + 4096 + t * 16);
        __syncthreads();
#pragma unroll
        for (int ks = 0; ks < 2; ++ks) {
            short8 af[2], bf[2];
#pragma unroll
            for (int it = 0; it < 2; ++it) {
                int m = wr + it * 32 + l31;
                int x = ((ks * 2 + lh) ^ ((m >> 1) & 3)) * 8;
                af[it] = *(const short8*)(const void*)(As + m * 32 + x);
            }
#pragma unroll
            for (int jt = 0; jt < 2; ++jt) {
                int n = wc + jt * 32 + l31;
                int x = ((ks * 2 + lh) ^ ((n >> 1) & 3)) * 8;
                bf[jt] = *(const short8*)(const void*)(Bs + n * 32 + x);
            }
#pragma unroll
            for (int it = 0; it < 2; ++it)
#pragma unroll
                for (int jt = 0; jt < 2; ++jt)
                    acc[it][jt] = __builtin_amdgcn_mfma_f32_32x32x16_bf16(af[it], bf[jt], acc[it][jt], 0, 0, 0);
        }
        __syncthreads();
    }

    // C/D layout (m74/m101): col = lane&31, row = (reg&3) + 8*(reg>>2) + 4*(lane>>5)
#pragma unroll
    for (int it = 0; it < 2; ++it) {
#pragma unroll
        for (int jt = 0; jt < 2; ++jt) {
            int col = col0 + wc + jt * 32 + l31;
            float bcol = bias[col];
#pragma unroll
            for (int reg = 0; reg < 16; ++reg) {
                int row = row0 + wr + it * 32 + (reg & 3) + 8 * (reg >> 2) + 4 * lh;
                float v = acc[it][jt][reg] + bcol;
                if (MODE == 0) {
                    ((ushort_t*)Cout)[(size_t)row * N + col] = f2bf(v);
                } else if (MODE == 1) {
                    ((float*)Cout)[(size_t)row * N + col] = v + res[(size_t)row * N + col];
                } else if (MODE == 2) {
                    v = v / (1.f + __expf(-v));
                    ((ushort_t*)Cout)[(size_t)row * N + col] = f2bf(v);
                } else { // 3
                    v = (v + res[(size_t)row * N + col]) * nm[row];
                    ((float*)Cout)[(size_t)row * N + col] = v;
                }
            }
        }
    }
}

// ---------------- MFMA attention: block = (b, h, q-tile of 64) ---------------
// q/k/v live in one merged buffer with row stride QS_ (q:+0, k:+1024, v:+2048).
__global__ __launch_bounds__(256) void attn_mfma_kernel(
    const ushort_t* __restrict__ qkv, const int* __restrict__ prio,
    const float* __restrict__ eb, const float* __restrict__ nm,
    ushort_t* __restrict__ out)
{
    int bid = blockIdx.x;
    int qt = bid & 3, h = (bid >> 2) & 15, b = bid >> 6;
    int t = threadIdx.x;

    __shared__ ushort_t Qs[64 * 72];     //  9216 B
    __shared__ ushort_t Ks[256 * 72];    // 36864 B (reused as Ps[64*264])
    __shared__ ushort_t Vt[64 * 264];    // 33792 B  (transposed V: [d][key])

    // ---- staging ----
    int lr = t >> 3, lc = (t & 7) * 8;
    const ushort_t* qg = qkv + ((size_t)(b * N_ + qt * 64)) * QS_ + h * HD_;
#pragma unroll
    for (int r = 0; r < 64; r += 32)
        *(uint4*)&Qs[(lr + r) * 72 + lc] = *(const uint4*)&qg[(size_t)(lr + r) * QS_ + lc];
    const ushort_t* kg = qkv + ((size_t)(b * N_)) * QS_ + 1024 + h * HD_;
#pragma unroll
    for (int r = 0; r < 256; r += 32)
        *(uint4*)&Ks[(lr + r) * 72 + lc] = *(const uint4*)&kg[(size_t)(lr + r) * QS_ + lc];
    const ushort_t* vg = qkv + ((size_t)(b * N_)) * QS_ + 2048 + h * HD_;
#pragma unroll
    for (int r = 0; r < 256; r += 32) {
        U16x8 uu; uu.u4 = *(const uint4*)&vg[(size_t)(lr + r) * QS_ + lc];
#pragma unroll
        for (int i = 0; i < 8; ++i)
            Vt[(lc + i) * 264 + lr + r] = uu.s[i];
    }
    __syncthreads();

    int lane = t & 63, c = lane & 15, quad = lane >> 4;
    int w = t >> 6;

    // ---- QK^T ----
    f32x4 z = {0.f, 0.f, 0.f, 0.f};
    f32x4 acc[16];
#pragma unroll
    for (int j = 0; j < 16; ++j) acc[j] = z;
    short8 aq0 = *(const short8*)(const void*)(Qs + (w * 16 + c) * 72 + quad * 8);
    short8 aq1 = *(const short8*)(const void*)(Qs + (w * 16 + c) * 72 + 32 + quad * 8);
#pragma unroll
    for (int j = 0; j < 16; ++j) {
        short8 b0 = *(const short8*)(const void*)(Ks + (j * 16 + c) * 72 + quad * 8);
        short8 b1 = *(const short8*)(const void*)(Ks + (j * 16 + c) * 72 + 32 + quad * 8);
        acc[j] = __builtin_amdgcn_mfma_f32_16x16x32_bf16(aq0, b0, acc[j], 0, 0, 0);
        acc[j] = __builtin_amdgcn_mfma_f32_16x16x32_bf16(aq1, b1, acc[j], 0, 0, 0);
    }

    // ---- scores: scale + edge bias + mask (C-layout: row=quad*4+r, col=j*16+c)
    int qbase = qt * 64 + w * 16 + quad * 4;   // +r, within-batch node index
    float nmq[4];
#pragma unroll
    for (int r = 0; r < 4; ++r) nmq[r] = nm[b * N_ + qbase + r];
#pragma unroll
    for (int j = 0; j < 16; ++j) {
        int key = j * 16 + c;
        float nmk = nm[b * N_ + key];
        const int* prp = prio + ((size_t)(b * N_ + qbase)) * N_ + key;
#pragma unroll
        for (int r = 0; r < 4; ++r) {
            int pr = prp[(size_t)r * N_];
            float bias = 0.f;
            bool adj = (key == qbase + r);
            if (pr >= 0) {
                int e = (pr >= E_) ? pr - E_ : pr;
                bias = eb[((size_t)b * E_ + e) * H_ + h];
                adj = true;
            }
            float val = acc[j][r] * 0.125f + bias;
            bool ok = adj && (nmq[r] != 0.f) && (nmk != 0.f);
            acc[j][r] = ok ? val : NEG_;
        }
    }

    // ---- softmax per row (16 lanes of a quad hold one row across 16 tiles) --
    float inv[4];
#pragma unroll
    for (int r = 0; r < 4; ++r) {
        float m = acc[0][r];
#pragma unroll
        for (int j = 1; j < 16; ++j) m = fmaxf(m, acc[j][r]);
        m = fmaxf(m, __shfl_xor(m, 1));
        m = fmaxf(m, __shfl_xor(m, 2));
        m = fmaxf(m, __shfl_xor(m, 4));
        m = fmaxf(m, __shfl_xor(m, 8));
        float s = 0.f;
#pragma unroll
        for (int j = 0; j < 16; ++j) {
            float p = __expf(acc[j][r] - m);
            acc[j][r] = p;
            s += p;
        }
        s += __shfl_xor(s, 1);
        s += __shfl_xor(s, 2);
        s += __shfl_xor(s, 4);
        s += __shfl_xor(s, 8);
        inv[r] = 1.f / s;
    }

    __syncthreads();            // everyone done reading Ks
    ushort_t* Ps = Ks;          // reuse as P [64][264]
#pragma unroll
    for (int j = 0; j < 16; ++j)
#pragma unroll
        for (int r = 0; r < 4; ++r)
            Ps[(w * 16 + quad * 4 + r) * 264 + j * 16 + c] = f2bf(acc[j][r] * inv[r]);
    __syncthreads();

    // ---- PV ----
    f32x4 oc[4];
#pragma unroll
    for (int dt = 0; dt < 4; ++dt) oc[dt] = z;
#pragma unroll
    for (int k0 = 0; k0 < 256; k0 += 32) {
        short8 ap = *(const short8*)(const void*)(Ps + (w * 16 + c) * 264 + k0 + quad * 8);
#pragma unroll
        for (int dt = 0; dt < 4; ++dt) {
            short8 bv = *(const short8*)(const void*)(Vt + (dt * 16 + c) * 264 + k0 + quad * 8);
            oc[dt] = __builtin_amdgcn_mfma_f32_16x16x32_bf16(ap, bv, oc[dt], 0, 0, 0);
        }
    }
    ushort_t* og = out + ((size_t)(b * N_ + qt * 64 + w * 16)) * D_ + h * HD_;
#pragma unroll
    for (int dt = 0; dt < 4; ++dt)
#pragma unroll
        for (int r = 0; r < 4; ++r)
            og[(size_t)(quad * 4 + r) * D_ + dt * 16 + c] = f2bf(oc[dt][r]);
}

extern "C" void kernel_launch(void* const* d_in, const int* in_sizes, int n_in,
                              void* d_out, int out_size, void* d_ws, size_t ws_size,
                              hipStream_t stream) {
    const float* x     = (const float*)d_in[0];
    const float* nm    = (const float*)d_in[1];
    const int*   edges = (const int*)d_in[2];
    const float* emask = (const float*)d_in[3];
    const float* remb  = (const float*)d_in[4];
    const float* ln_g  = (const float*)d_in[5];
    const float* ln_b  = (const float*)d_in[6];
    const float* Wq = (const float*)d_in[7];  const float* bq = (const float*)d_in[8];
    const float* Wk = (const float*)d_in[9];  const float* bk = (const float*)d_in[10];
    const float* Wv = (const float*)d_in[11]; const float* bv = (const float*)d_in[12];
    const float* We = (const float*)d_in[13]; const float* be = (const float*)d_in[14];
    const float* Wo = (const float*)d_in[15]; const float* bo = (const float*)d_in[16];
    const float* ff_g = (const float*)d_in[17]; const float* ff_b = (const float*)d_in[18];
    const float* W1 = (const float*)d_in[19]; const float* b1 = (const float*)d_in[20];
    const float* W2 = (const float*)d_in[21]; const float* b2 = (const float*)d_in[22];
    float* out = (float*)d_out;

    char* ws = (char*)d_ws;
    const size_t MB = 1ll << 20;
    int*      prio = (int*)ws;                       // 0..8 MB
    float*    ebuf = (float*)(ws + 8 * MB);          // 8..9 MB
    ushort_t* xn   = (ushort_t*)(ws + 9 * MB);       // 9..25 MB (reused: attn_out)
    float*    x2   = (float*)(ws + 25 * MB);         // 25..57 MB
    ushort_t* hn   = (ushort_t*)(ws + 57 * MB);      // 57..73 MB
    ushort_t* qkv  = (ushort_t*)(ws + 73 * MB);      // 73..121 MB [8192][3072]
    ushort_t* mid  = qkv;                            // 73..137 MB (qkv dead by then)
    ushort_t* qkvT = (ushort_t*)(ws + 137 * MB);     // 137..143 MB [3072][1024]
    ushort_t* WoT  = (ushort_t*)(ws + 143 * MB);     // 143..145 MB
    ushort_t* W1T  = (ushort_t*)(ws + 145 * MB);     // 145..153 MB [4096][1024]
    ushort_t* W2T  = (ushort_t*)(ws + 153 * MB);     // 153..161 MB [1024][4096]
    float*    cb   = (float*)(ws + 161 * MB);        // 161..161.02 MB [3072]
    ushort_t* aout = xn;

    const int M = B_ * N_;   // 8192

    (void)hipMemsetAsync(prio, 0xFF, (size_t)B_ * N_ * N_ * sizeof(int), stream);
    eb_kernel<<<B_ * E_ / 16, 256, 0, stream>>>(remb, We, be, ebuf);
    scatter_kernel<<<(B_ * E_ + 255) / 256, 256, 0, stream>>>(edges, emask, prio);

    prep_kernel<<<12300, 256, 0, stream>>>(Wq, Wk, Wv, Wo, W1, W2, bq, bk, bv,
                                           qkvT, WoT, W1T, W2T, cb);

    ln_bf16_kernel<<<M, 256, 0, stream>>>(x, ln_g, ln_b, xn);

    gemm_bf16<0><<<dim3(24, 64), 256, 0, stream>>>(xn, qkvT, cb, nullptr, nullptr, qkv, M, QS_, D_);

    attn_mfma_kernel<<<B_ * H_ * 4, 256, 0, stream>>>(qkv, prio, ebuf, nm, aout);

    gemm_bf16<1><<<dim3(8, 64), 256, 0, stream>>>(aout, WoT, bo, x, nullptr, x2, M, D_, D_);
    ln_bf16_kernel<<<M, 256, 0, stream>>>(x2, ff_g, ff_b, hn);

    gemm_bf16<2><<<dim3(32, 64), 256, 0, stream>>>(hn, W1T, b1, nullptr, nullptr, mid, M, 4 * D_, D_);
    gemm_bf16<3><<<dim3(8, 64), 256, 0, stream>>>(mid, W2T, b2, x2, nm, out, M, D_, 4 * D_);
}